// Round 2
// baseline (171.921 us; speedup 1.0000x reference)
//
#include <hip/hip_runtime.h>

// STKBranch double-softmax attention, f16-MFMA 2-pass, R13:
//   - FAT WAVES: 4 waves x 32 q-rows (was 8 x 16), 256-thread blocks, ROWS=128.
//     Each wave reads the full K/V LDS tile per iteration regardless of q-count,
//     so halving the wave count halves LDS read traffic + barrier syncs per
//     unit work. Grid stays 512 -> 2 independent blocks/CU overlap stalls.
//   - keeps R12 structure: swapped QK^T (C=KxQ^T) so P feeds PV directly from
//     registers as the 16x16x16 B-fragment; no Ps/Qs LDS; Ks/Vt double-buffered;
//     reg prefetch kt+2; 1 barrier/tile; scale*2*log2e folded into Q frags.
// Math: L = scale*q@k^T ; w = softmax(2L) ; attn = softmax(L*w) ; out = attn@v
// |L| <= ~7 -> no max-subtraction. B=4 H=8 N=2048 D=64 fp32 io.

typedef _Float16 f16;
typedef f16 f16x8 __attribute__((ext_vector_type(8)));
typedef f16 f16x4 __attribute__((ext_vector_type(4)));
typedef float f32x4 __attribute__((ext_vector_type(4)));

#define MFMA32(a, b, c) __builtin_amdgcn_mfma_f32_16x16x32_f16((a), (b), (c), 0, 0, 0)
#define MFMA16(a, b, c) __builtin_amdgcn_mfma_f32_16x16x16f16((a), (b), (c), 0, 0, 0)
#define EXP2(x) __builtin_amdgcn_exp2f(x)   // v_exp_f32: D = 2^S0

#define N_CTX 2048
#define DH 64
#define KT 64
#define NKT (N_CTX / KT)
#define ROWS 128          // 4 waves x 32 q-rows
#define QS 72             // universal LDS row stride (f16): 144 B

#define C2 2.885390081777927f    // 2*log2(e), folded into Q fragments

__device__ inline unsigned pk(float a, float b) {
    typedef __fp16 fp16x2_t __attribute__((ext_vector_type(2)));
    union { fp16x2_t v; unsigned u; } x;
    x.v = __builtin_amdgcn_cvt_pkrtz(a, b);
    return x.u;
}

__global__ __launch_bounds__(256, 2)
void stk_attn_mfma(const float* __restrict__ qg, const float* __restrict__ kg,
                   const float* __restrict__ vglob, const float* __restrict__ sg,
                   float* __restrict__ og) {
    __shared__ f16 Ks[2][KT * QS];      // 18432 B (double-buffered), [key][d]
    __shared__ f16 Vt[2][DH * QS];      // 18432 B (double-buffered), [d][key]
                                        // total 36864 B

    const int tid  = threadIdx.x;
    const int wv   = tid >> 6;        // 0..3
    const int lane = tid & 63;
    const int l15  = lane & 15;
    const int q4   = lane >> 4;
    const int vp   = tid & 31;        // V staging: key pair (2vp, 2vp+1)
    const int vgr  = tid >> 5;        // V staging: d-octet (0..7 -> d = vgr*8..+7)
    const int bh   = blockIdx.x & 31; // XCD swizzle: head h -> blocks h+32j -> XCD h%8
    const int q0   = (blockIdx.x >> 5) * ROWS;
    const float scale2 = sg[0] * C2;  // fold 2*log2e: acc = 2L*log2e

    const float* qb = qg + (size_t)bh * N_CTX * DH;
    const float* kb = kg + (size_t)bh * N_CTX * DH;
    const float* vb = vglob + (size_t)bh * N_CTX * DH;
    float*       ob = og + (size_t)bh * N_CTX * DH;

    // ---- Q fragments direct from global: 2 q-subtiles per wave ----
    // B operand of swapped QK^T: B[k=q4*8+e][col=l15] = Q[row][k]*scale2,
    // row = q0 + wv*32 + qc*16 + l15.
    f16x8 aq[2][2];
    #pragma unroll
    for (int qc = 0; qc < 2; ++qc) {
        const float* qrow = qb + (size_t)(q0 + wv * 32 + qc * 16 + l15) * DH;
        #pragma unroll
        for (int kc = 0; kc < 2; ++kc) {
            float4 a0 = *(const float4*)&qrow[kc * 32 + q4 * 8];
            float4 a1 = *(const float4*)&qrow[kc * 32 + q4 * 8 + 4];
            union { f16x8 h; unsigned u[4]; } A;
            A.u[0] = pk(a0.x * scale2, a0.y * scale2);
            A.u[1] = pk(a0.z * scale2, a0.w * scale2);
            A.u[2] = pk(a1.x * scale2, a1.y * scale2);
            A.u[3] = pk(a1.z * scale2, a1.w * scale2);
            aq[qc][kc] = A.h;
        }
    }

    // loop-invariant LDS lane bases (all ds offsets below are immediates)
    f16* const ks_w  = &Ks[0][0];                        // + staging idx
    const f16* const ks_r = &Ks[0][l15 * QS + q4 * 8];   // A-frag of QK^T: K row l15
    f16* const vt_w  = &Vt[0][(vgr * 8) * QS + 2 * vp];
    const f16* const vt_r = &Vt[0][l15 * QS + q4 * 4];   // A-frag of PV: V^T row l15
    const int KSB = KT * QS;                             // Ks/Vt buffer stride (f16)

    // =============== PASS 1: s1 = sum_k exp(2L) per q-row ===============
    float s1[2] = {0.f, 0.f};
    float4 kr[4];
    #pragma unroll
    for (int it = 0; it < 4; ++it) {
        int idx = it * 256 + tid;
        kr[it] = *(const float4*)&kb[((size_t)(idx >> 4)) * DH + (idx & 15) * 4];
    }
    #pragma unroll
    for (int it = 0; it < 4; ++it) {
        int idx = it * 256 + tid;
        *(uint2*)&ks_w[(idx >> 4) * QS + (idx & 15) * 4] =
            make_uint2(pk(kr[it].x, kr[it].y), pk(kr[it].z, kr[it].w));
    }
    #pragma unroll
    for (int it = 0; it < 4; ++it) {
        int idx = it * 256 + tid;
        kr[it] = *(const float4*)&kb[((size_t)KT + (idx >> 4)) * DH + (idx & 15) * 4];
    }
    __syncthreads();

    for (int kt = 0; kt < NKT; ++kt) {
        const int cur = (kt & 1) * KSB, nxt = KSB - cur;
        #pragma unroll
        for (int it = 0; it < 4; ++it) {
            int idx = it * 256 + tid;
            *(uint2*)&ks_w[nxt + (idx >> 4) * QS + (idx & 15) * 4] =
                make_uint2(pk(kr[it].x, kr[it].y), pk(kr[it].z, kr[it].w));
        }
        {
            int tn = (kt + 2 < NKT) ? kt + 2 : NKT - 1;
            #pragma unroll
            for (int it = 0; it < 4; ++it) {
                int idx = it * 256 + tid;
                kr[it] = *(const float4*)&kb[((size_t)tn * KT + (idx >> 4)) * DH + (idx & 15) * 4];
            }
        }
        #pragma unroll
        for (int kgi = 0; kgi < 4; ++kgi) {
            f16x8 b0 = *(const f16x8*)&ks_r[cur + kgi * 16 * QS];
            f16x8 b1 = *(const f16x8*)&ks_r[cur + kgi * 16 * QS + 32];
            #pragma unroll
            for (int qc = 0; qc < 2; ++qc) {
                f32x4 acc = {0.f, 0.f, 0.f, 0.f};
                acc = MFMA32(b0, aq[qc][0], acc);   // swapped: C[key][q], lane q = l15
                acc = MFMA32(b1, aq[qc][1], acc);
                s1[qc] += EXP2(acc[0]);
                s1[qc] += EXP2(acc[1]);
                s1[qc] += EXP2(acc[2]);
                s1[qc] += EXP2(acc[3]);
            }
        }
        __syncthreads();
    }
    // reduce across q4 groups (key partitions): lanes l15, l15+16, l15+32, l15+48
    float inv1[2];
    #pragma unroll
    for (int qc = 0; qc < 2; ++qc) {
        float v = s1[qc];
        v += __shfl_xor(v, 16, 64);
        v += __shfl_xor(v, 32, 64);
        inv1[qc] = 0.5f / v;    // e2 = exp2((acc*e1) * 0.5/s1)  [acc = 2L*log2e]
    }

    // =============== PASS 2: e2, O^T += V^T P^T ===============
    float l2[2] = {0.f, 0.f};
    f32x4 O[2][4];
    #pragma unroll
    for (int qc = 0; qc < 2; ++qc)
        #pragma unroll
        for (int dt = 0; dt < 4; ++dt) O[qc][dt] = (f32x4){0.f, 0.f, 0.f, 0.f};

    float4 vr0, vr1, vr2, vr3;  // V prefetch: keys 2vp/2vp+1, d = vgr*8..+7
    // prologue: Ks[0]<-K(0), Vt[0]<-V(0); kr<-K(1), vr<-V(1)
    #pragma unroll
    for (int it = 0; it < 4; ++it) {
        int idx = it * 256 + tid;
        kr[it] = *(const float4*)&kb[((size_t)(idx >> 4)) * DH + (idx & 15) * 4];
    }
    #pragma unroll
    for (int it = 0; it < 4; ++it) {
        int idx = it * 256 + tid;
        *(uint2*)&ks_w[(idx >> 4) * QS + (idx & 15) * 4] =
            make_uint2(pk(kr[it].x, kr[it].y), pk(kr[it].z, kr[it].w));
    }
    {
        const float* vs = vb + ((size_t)(2 * vp)) * DH + vgr * 8;
        float4 a0 = *(const float4*)(vs);
        float4 a1 = *(const float4*)(vs + 4);
        float4 b0 = *(const float4*)(vs + DH);
        float4 b1 = *(const float4*)(vs + DH + 4);
        #pragma unroll
        for (int j = 0; j < 4; ++j) {
            *(unsigned*)&vt_w[j * QS] = pk(((const float*)&a0)[j], ((const float*)&b0)[j]);
            *(unsigned*)&vt_w[(4 + j) * QS] = pk(((const float*)&a1)[j], ((const float*)&b1)[j]);
        }
        const float* vs1 = vb + ((size_t)(KT + 2 * vp)) * DH + vgr * 8;
        vr0 = *(const float4*)(vs1);
        vr1 = *(const float4*)(vs1 + 4);
        vr2 = *(const float4*)(vs1 + DH);
        vr3 = *(const float4*)(vs1 + DH + 4);
    }
    #pragma unroll
    for (int it = 0; it < 4; ++it) {
        int idx = it * 256 + tid;
        kr[it] = *(const float4*)&kb[((size_t)KT + (idx >> 4)) * DH + (idx & 15) * 4];
    }
    __syncthreads();

    for (int kt = 0; kt < NKT; ++kt) {
        const int cur = (kt & 1) * KSB, nxt = KSB - cur;
        // stage next K/V tile into the other buffers (overlaps all compute below)
        #pragma unroll
        for (int it = 0; it < 4; ++it) {
            int idx = it * 256 + tid;
            *(uint2*)&ks_w[nxt + (idx >> 4) * QS + (idx & 15) * 4] =
                make_uint2(pk(kr[it].x, kr[it].y), pk(kr[it].z, kr[it].w));
        }
        #pragma unroll
        for (int j = 0; j < 4; ++j) {
            *(unsigned*)&vt_w[nxt + j * QS] = pk(((const float*)&vr0)[j], ((const float*)&vr2)[j]);
            *(unsigned*)&vt_w[nxt + (4 + j) * QS] = pk(((const float*)&vr1)[j], ((const float*)&vr3)[j]);
        }
        // QK^T (swapped) on Ks[cur] + softmax chain; P stays in registers as
        // the ready-made B-fragment of the 16x16x16 PV MFMA.
        f16x4 pfr[2][4];
        #pragma unroll
        for (int kgi = 0; kgi < 4; ++kgi) {
            f16x8 b0 = *(const f16x8*)&ks_r[cur + kgi * 16 * QS];
            f16x8 b1 = *(const f16x8*)&ks_r[cur + kgi * 16 * QS + 32];
            #pragma unroll
            for (int qc = 0; qc < 2; ++qc) {
                f32x4 acc = {0.f, 0.f, 0.f, 0.f};
                acc = MFMA32(b0, aq[qc][0], acc);
                acc = MFMA32(b1, aq[qc][1], acc);
                float e2r[4];
                #pragma unroll
                for (int r = 0; r < 4; ++r) {
                    float a  = acc[r];
                    float e1 = EXP2(a);
                    float e2 = EXP2((a * e1) * inv1[qc]);
                    l2[qc] += e2;
                    e2r[r] = e2;
                }
                union { f16x4 h; unsigned u[2]; } P;
                P.u[0] = pk(e2r[0], e2r[1]);
                P.u[1] = pk(e2r[2], e2r[3]);
                pfr[qc][kgi] = P.h;
            }
        }
        // prefetch K(kt+2), V(kt+2) (clamped; loads in flight during PV)
        {
            int tn = (kt + 2 < NKT) ? kt + 2 : NKT - 1;
            #pragma unroll
            for (int it = 0; it < 4; ++it) {
                int idx = it * 256 + tid;
                kr[it] = *(const float4*)&kb[((size_t)tn * KT + (idx >> 4)) * DH + (idx & 15) * 4];
            }
            const float* vs = vb + ((size_t)tn * KT + 2 * vp) * DH + vgr * 8;
            vr0 = *(const float4*)(vs);
            vr1 = *(const float4*)(vs + 4);
            vr2 = *(const float4*)(vs + DH);
            vr3 = *(const float4*)(vs + DH + 4);
        }
        // PV: O^T[d][q] += sum_key V^T[d][key] * P^T[key][q], 16x16x16 MFMA,
        // A-fragment (V^T row dt*16+l15, keys kgi*16+q4*4..) shared across qc.
        #pragma unroll
        for (int kgi = 0; kgi < 4; ++kgi) {
            #pragma unroll
            for (int dt = 0; dt < 4; ++dt) {
                f16x4 av = *(const f16x4*)&vt_r[cur + dt * 16 * QS + kgi * 16];
                O[0][dt] = MFMA16(av, pfr[0][kgi], O[0][dt]);
                O[1][dt] = MFMA16(av, pfr[1][kgi], O[1][dt]);
            }
        }
        __syncthreads();   // swap: protects Ks/Vt cur<->nxt for next iteration
    }

    // ---- finalize: lane holds O^T[d = dt*16+q4*4+r][q = wv*32+qc*16+l15] ----
    #pragma unroll
    for (int qc = 0; qc < 2; ++qc) {
        float v = l2[qc];
        v += __shfl_xor(v, 16, 64);
        v += __shfl_xor(v, 32, 64);
        const float invl2 = 1.0f / v;
        const size_t orow = (size_t)(q0 + wv * 32 + qc * 16 + l15) * DH;
        #pragma unroll
        for (int dt = 0; dt < 4; ++dt) {
            float4 o;
            o.x = O[qc][dt][0] * invl2;
            o.y = O[qc][dt][1] * invl2;
            o.z = O[qc][dt][2] * invl2;
            o.w = O[qc][dt][3] * invl2;
            *(float4*)&ob[orow + dt * 16 + q4 * 4] = o;
        }
    }
}

extern "C" void kernel_launch(void* const* d_in, const int* in_sizes, int n_in,
                              void* d_out, int out_size, void* d_ws, size_t ws_size,
                              hipStream_t stream) {
    const float* q = (const float*)d_in[0];
    const float* k = (const float*)d_in[1];
    const float* v = (const float*)d_in[2];
    const float* s = (const float*)d_in[3];
    float* out = (float*)d_out;
    dim3 grid(32 * 16);   // bh = blockIdx&31 (XCD swizzle), q-tile = blockIdx>>5
    stk_attn_mfma<<<grid, 256, 0, stream>>>(q, k, v, s, out);
}